// Round 18
// baseline (283.264 us; speedup 1.0000x reference)
//
#include <hip/hip_runtime.h>
#include <hip/hip_bf16.h>

// GCN: h1 = relu(Â (x W1) + b1); h2 = relu(Â (h1 W2) + b2);
// out = mean_pool(h2, batch) @ Wlin + blin,  Â = D^-1/2 (A+I) D^-1/2
//
// R5/R6: bucketed CSR build, deterministic two-pass, zero global atomics.
// R7: xws bf16 -> gather row 128 B.
// R8/R9 LESSON: sub-dword per-lane global stores defeat L2 write-merge.
// R10/R17 LESSON: gather is outstanding-miss-slot bound -- wider loads and
//     more loads in flight both pay off linearly-ish.
// R12 LESSON: multi-NODE gather unroll spills. One node context per wave.
// R14 LESSON: same-address atomic chains ~125 ns/link; keep <= ~100.
// R15/R16: replicated pooled accumulators (32x) decouple chains from occupancy.
// R18: gather core v4 -- quarter-wave per row: lane (q,p) loads 8 B (4 bf16),
//     one instr covers 4 edges; 16-edge tier = 4 loads, 16 rows in flight.
//     Butterfly shfl_xor(16/32); lane returns dim d=4p+q. Single node
//     context (R12-safe). Applied to agg_k and aggpool_k.

#define NDIM 64
#define NGRAPH 64
#define NREP 32
#define BSHIFT 7                      // 128 nodes per bucket
#define BNODES 128
#define ECHUNK 8192                   // edges per block in bincnt/bscatter (32/thread)

__device__ __forceinline__ unsigned short f32_to_bf16(float f) {
    unsigned int u = __float_as_uint(f);
    unsigned int r = 0x7FFFu + ((u >> 16) & 1u);   // round-to-nearest-even
    return (unsigned short)((u + r) >> 16);
}

// ---- pass 1: per-(block,bucket) edge counts via LDS histogram ----
__global__ void bincnt_k(const int* __restrict__ dst, int* __restrict__ cntmat,
                         int e, int nb) {
    extern __shared__ int hist[];
    int t = threadIdx.x;
    for (int i = t; i < nb; i += 256) hist[i] = 0;
    __syncthreads();
    int base = blockIdx.x * ECHUNK + t;
#pragma unroll
    for (int k = 0; k < 32; ++k) {
        int i = base + k * 256;
        if (i < e) atomicAdd(&hist[dst[i] >> BSHIFT], 1);   // LDS atomic
    }
    __syncthreads();
    long row = (long)blockIdx.x * nb;
    for (int i = t; i < nb; i += 256) cntmat[row + i] = hist[i];
}

// ---- pass 2: per-bucket exclusive scan across blocks (one block per bucket) ----
__global__ void colscan_k(const int* __restrict__ cntmat, int* __restrict__ basemat,
                          int* __restrict__ bucketTot, int nblk, int nb) {
    __shared__ int s[256];
    int b = blockIdx.x;
    int t = threadIdx.x;
    int v = (t < nblk) ? cntmat[(long)t * nb + b] : 0;
    s[t] = v;
    __syncthreads();
    for (int off = 1; off < 256; off <<= 1) {
        int tmp = (t >= off) ? s[t - off] : 0;
        __syncthreads();
        s[t] += tmp;
        __syncthreads();
    }
    if (t < nblk) basemat[(long)t * nb + b] = s[t] - v;   // exclusive within column
    if (t == 255) bucketTot[b] = s[255];
}

// ---- pass 3: exclusive scan of bucket totals (single block, nb<=1024) ----
__global__ void bscan_k(const int* __restrict__ bucketTot, int* __restrict__ bucketStart,
                        int* __restrict__ start, int nb, int n, int e) {
    __shared__ int s[1024];
    int t = threadIdx.x;
    int v = (t < nb) ? bucketTot[t] : 0;
    s[t] = v;
    __syncthreads();
    for (int off = 1; off < 1024; off <<= 1) {
        int tmp = (t >= off) ? s[t - off] : 0;
        __syncthreads();
        s[t] += tmp;
        __syncthreads();
    }
    if (t < nb) bucketStart[t + 1] = s[t];
    if (t == 0) { bucketStart[0] = 0; start[n] = e; }   // CSR sentinel
}

// ---- pass 4: scatter packed (dst_local<<25 | src) via block-private LDS cursors ----
__global__ void bscatter_k(const int* __restrict__ src, const int* __restrict__ dst,
                           const int* __restrict__ bucketStart,
                           const int* __restrict__ basemat,
                           unsigned int* __restrict__ ebuf, int e, int nb) {
    extern __shared__ int cur[];
    int t = threadIdx.x;
    long row = (long)blockIdx.x * nb;
    for (int i = t; i < nb; i += 256) cur[i] = bucketStart[i] + basemat[row + i];
    __syncthreads();
    int base = blockIdx.x * ECHUNK + t;
#pragma unroll
    for (int k = 0; k < 32; ++k) {
        int i = base + k * 256;
        if (i < e) {
            int d = dst[i];
            int b = d >> BSHIFT;
            int pos = atomicAdd(&cur[b], 1);               // LDS atomic, block-private
            ebuf[pos] = ((unsigned)(d & (BNODES - 1)) << 25) | (unsigned)src[i];
        }
    }
}

// ---- pass 5: one block per bucket -> dst-ordered CSR slice, dinv, graph ranges ----
__global__ void fill2_k(const unsigned int* __restrict__ ebuf,
                        const int* __restrict__ bucketStart,
                        const int* __restrict__ batch, float* __restrict__ dinv,
                        int* __restrict__ start, int* __restrict__ csr,
                        int* __restrict__ gstart, int* __restrict__ gend, int n) {
    __shared__ int scnt[BNODES], sincl[BNODES], scur[BNODES];
    int t = threadIdx.x;
    int b = blockIdx.x;
    int node0 = b << BSHIFT;
    int nNodes = min(BNODES, n - node0);
    if (t < BNODES) scnt[t] = 0;
    int e0 = bucketStart[b], e1 = bucketStart[b + 1];
    __syncthreads();
    for (int i = e0 + t; i < e1; i += 256)
        atomicAdd(&scnt[ebuf[i] >> 25], 1);
    __syncthreads();
    int val = (t < BNODES) ? scnt[t] : 0;
    if (t < BNODES) sincl[t] = val;
    __syncthreads();
    for (int off = 1; off < BNODES; off <<= 1) {
        int tmp = (t >= off && t < BNODES) ? sincl[t - off] : 0;
        __syncthreads();
        if (t < BNODES) sincl[t] += tmp;
        __syncthreads();
    }
    if (t < nNodes) {
        int v = node0 + t;
        int st = e0 + sincl[t] - val;     // exclusive within bucket
        start[v] = st;
        scur[t] = st;
        dinv[v] = rsqrtf((float)(val + 1));
        int g = batch[v];                 // sorted-batch boundary detection
        if (v == 0 || batch[v - 1] != g) gstart[g] = v;
        if (v == n - 1 || batch[v + 1] != g) gend[g] = v + 1;
    }
    __syncthreads();
    for (int i = e0 + t; i < e1; i += 256) {
        unsigned rec = ebuf[i];
        int pos = atomicAdd(&scur[rec >> 25], 1);
        csr[pos] = (int)(rec & 0x1FFFFFFu);   // scatter within L2-local 8 KB slice
    }
}

// ---- dense GEMM v4  C[n,64](bf16 pairs) = scale[row] * (A[n,64] @ W[64,64]) ----
__global__ void gemm_k(const float* __restrict__ A, const float* __restrict__ W,
                       const float* __restrict__ scale,
                       unsigned long long* __restrict__ C, int n) {
    __shared__ float4 Wl4[64 * 16];   // 16 KB: W[k][4c..4c+3]
    __shared__ float4 Xl4[64 * 16];   // 16 KB: X[r][4k..4k+3]
    int t = threadIdx.x;
    const float4* W4 = (const float4*)W;
#pragma unroll
    for (int i = 0; i < 4; ++i) Wl4[t + 256 * i] = W4[t + 256 * i];
    const float4* A4 = (const float4*)A;
    long fbase = (long)blockIdx.x * 1024;
    long fmax  = (long)n * 16;
#pragma unroll
    for (int i = 0; i < 4; ++i) {
        long f = fbase + t + 256 * i;
        float4 v;
        if (f < fmax) v = A4[f];
        else { v.x = 0.f; v.y = 0.f; v.z = 0.f; v.w = 0.f; }
        Xl4[t + 256 * i] = v;
    }
    __syncthreads();
    int rg = t >> 4, cg = t & 15;
    float a00 = 0.f, a01 = 0.f, a02 = 0.f, a03 = 0.f;
    float a10 = 0.f, a11 = 0.f, a12 = 0.f, a13 = 0.f;
    float a20 = 0.f, a21 = 0.f, a22 = 0.f, a23 = 0.f;
    float a30 = 0.f, a31 = 0.f, a32 = 0.f, a33 = 0.f;
#pragma unroll 4
    for (int k4 = 0; k4 < 16; ++k4) {
        float4 w0 = Wl4[(4 * k4 + 0) * 16 + cg];
        float4 w1 = Wl4[(4 * k4 + 1) * 16 + cg];
        float4 w2 = Wl4[(4 * k4 + 2) * 16 + cg];
        float4 w3 = Wl4[(4 * k4 + 3) * 16 + cg];
        float4 x0 = Xl4[(4 * rg + 0) * 16 + k4];
        float4 x1 = Xl4[(4 * rg + 1) * 16 + k4];
        float4 x2 = Xl4[(4 * rg + 2) * 16 + k4];
        float4 x3 = Xl4[(4 * rg + 3) * 16 + k4];
        a00 += x0.x * w0.x + x0.y * w1.x + x0.z * w2.x + x0.w * w3.x;
        a01 += x0.x * w0.y + x0.y * w1.y + x0.z * w2.y + x0.w * w3.y;
        a02 += x0.x * w0.z + x0.y * w1.z + x0.z * w2.z + x0.w * w3.z;
        a03 += x0.x * w0.w + x0.y * w1.w + x0.z * w2.w + x0.w * w3.w;
        a10 += x1.x * w0.x + x1.y * w1.x + x1.z * w2.x + x1.w * w3.x;
        a11 += x1.x * w0.y + x1.y * w1.y + x1.z * w2.y + x1.w * w3.y;
        a12 += x1.x * w0.z + x1.y * w1.z + x1.z * w2.z + x1.w * w3.z;
        a13 += x1.x * w0.w + x1.y * w1.w + x1.z * w2.w + x1.w * w3.w;
        a20 += x2.x * w0.x + x2.y * w1.x + x2.z * w2.x + x2.w * w3.x;
        a21 += x2.x * w0.y + x2.y * w1.y + x2.z * w2.y + x2.w * w3.y;
        a22 += x2.x * w0.z + x2.y * w1.z + x2.z * w2.z + x2.w * w3.z;
        a23 += x2.x * w0.w + x2.y * w1.w + x2.z * w2.w + x2.w * w3.w;
        a30 += x3.x * w0.x + x3.y * w1.x + x3.z * w2.x + x3.w * w3.x;
        a31 += x3.x * w0.y + x3.y * w1.y + x3.z * w2.y + x3.w * w3.y;
        a32 += x3.x * w0.z + x3.y * w1.z + x3.z * w2.z + x3.w * w3.z;
        a33 += x3.x * w0.w + x3.y * w1.w + x3.z * w2.w + x3.w * w3.w;
    }
    int vb = blockIdx.x * 64 + rg * 4;
    int v;
    float s;
    unsigned long long u;
    v = vb + 0;
    if (v < n) {
        s = scale[v];
        u  = (unsigned long long)(((unsigned int)f32_to_bf16(s * a01) << 16) | (unsigned int)f32_to_bf16(s * a00));
        u |= (unsigned long long)(((unsigned int)f32_to_bf16(s * a03) << 16) | (unsigned int)f32_to_bf16(s * a02)) << 32;
        C[(long)v * 16 + cg] = u;
    }
    v = vb + 1;
    if (v < n) {
        s = scale[v];
        u  = (unsigned long long)(((unsigned int)f32_to_bf16(s * a11) << 16) | (unsigned int)f32_to_bf16(s * a10));
        u |= (unsigned long long)(((unsigned int)f32_to_bf16(s * a13) << 16) | (unsigned int)f32_to_bf16(s * a12)) << 32;
        C[(long)v * 16 + cg] = u;
    }
    v = vb + 2;
    if (v < n) {
        s = scale[v];
        u  = (unsigned long long)(((unsigned int)f32_to_bf16(s * a21) << 16) | (unsigned int)f32_to_bf16(s * a20));
        u |= (unsigned long long)(((unsigned int)f32_to_bf16(s * a23) << 16) | (unsigned int)f32_to_bf16(s * a22)) << 32;
        C[(long)v * 16 + cg] = u;
    }
    v = vb + 3;
    if (v < n) {
        s = scale[v];
        u  = (unsigned long long)(((unsigned int)f32_to_bf16(s * a31) << 16) | (unsigned int)f32_to_bf16(s * a30));
        u |= (unsigned long long)(((unsigned int)f32_to_bf16(s * a33) << 16) | (unsigned int)f32_to_bf16(s * a32)) << 32;
        C[(long)v * 16 + cg] = u;
    }
}

// ---- gather core v4 (R18): quarter-wave per row, 4 edges per instruction ----
// Lane (q=lane>>4, p=lane&15) loads 8 B (dims 4p..4p+3) of edge i+q (+4 etc).
// 16-edge tier = 4 loads/lane, 16 rows in flight. Butterfly xor(16/32).
// ONE node context, named scalars only. Returns dim d=4p+q (self-loop incl).
__device__ __forceinline__ float gather_row(const unsigned long long* __restrict__ xp8,
                                            const int* __restrict__ csr,
                                            int s0, int d0, int q, int p, int v) {
    float a0, a1, a2, a3;
    {
        unsigned long long u = (q == 0) ? xp8[(long)v * 16 + p] : 0ull;  // self loop once
        a0 = __uint_as_float((unsigned int)(u & 0xFFFFu) << 16);
        a1 = __uint_as_float((unsigned int)u & 0xFFFF0000u);
        a2 = __uint_as_float((unsigned int)((u >> 32) & 0xFFFFu) << 16);
        a3 = __uint_as_float((unsigned int)(u >> 48) << 16);
    }
    float b0 = 0.f, b1 = 0.f, b2 = 0.f, b3 = 0.f;
    int i = 0;
    for (; i + 16 <= d0; i += 16) {       // 4 loads/lane, 16 rows in flight
        int j0 = csr[s0 + i +  0 + q];
        int j1 = csr[s0 + i +  4 + q];
        int j2 = csr[s0 + i +  8 + q];
        int j3 = csr[s0 + i + 12 + q];
        unsigned long long u0 = xp8[(long)j0 * 16 + p];
        unsigned long long u1 = xp8[(long)j1 * 16 + p];
        unsigned long long u2 = xp8[(long)j2 * 16 + p];
        unsigned long long u3 = xp8[(long)j3 * 16 + p];
        a0 += __uint_as_float((unsigned int)(u0 & 0xFFFFu) << 16);
        a1 += __uint_as_float((unsigned int)u0 & 0xFFFF0000u);
        a2 += __uint_as_float((unsigned int)((u0 >> 32) & 0xFFFFu) << 16);
        a3 += __uint_as_float((unsigned int)(u0 >> 48) << 16);
        b0 += __uint_as_float((unsigned int)(u1 & 0xFFFFu) << 16);
        b1 += __uint_as_float((unsigned int)u1 & 0xFFFF0000u);
        b2 += __uint_as_float((unsigned int)((u1 >> 32) & 0xFFFFu) << 16);
        b3 += __uint_as_float((unsigned int)(u1 >> 48) << 16);
        a0 += __uint_as_float((unsigned int)(u2 & 0xFFFFu) << 16);
        a1 += __uint_as_float((unsigned int)u2 & 0xFFFF0000u);
        a2 += __uint_as_float((unsigned int)((u2 >> 32) & 0xFFFFu) << 16);
        a3 += __uint_as_float((unsigned int)(u2 >> 48) << 16);
        b0 += __uint_as_float((unsigned int)(u3 & 0xFFFFu) << 16);
        b1 += __uint_as_float((unsigned int)u3 & 0xFFFF0000u);
        b2 += __uint_as_float((unsigned int)((u3 >> 32) & 0xFFFFu) << 16);
        b3 += __uint_as_float((unsigned int)(u3 >> 48) << 16);
    }
    for (; i + 8 <= d0; i += 8) {         // 2 loads/lane
        int j0 = csr[s0 + i + 0 + q];
        int j1 = csr[s0 + i + 4 + q];
        unsigned long long u0 = xp8[(long)j0 * 16 + p];
        unsigned long long u1 = xp8[(long)j1 * 16 + p];
        a0 += __uint_as_float((unsigned int)(u0 & 0xFFFFu) << 16);
        a1 += __uint_as_float((unsigned int)u0 & 0xFFFF0000u);
        a2 += __uint_as_float((unsigned int)((u0 >> 32) & 0xFFFFu) << 16);
        a3 += __uint_as_float((unsigned int)(u0 >> 48) << 16);
        b0 += __uint_as_float((unsigned int)(u1 & 0xFFFFu) << 16);
        b1 += __uint_as_float((unsigned int)u1 & 0xFFFF0000u);
        b2 += __uint_as_float((unsigned int)((u1 >> 32) & 0xFFFFu) << 16);
        b3 += __uint_as_float((unsigned int)(u1 >> 48) << 16);
    }
    for (; i + 4 <= d0; i += 4) {         // 1 load/lane
        int j = csr[s0 + i + q];
        unsigned long long u = xp8[(long)j * 16 + p];
        a0 += __uint_as_float((unsigned int)(u & 0xFFFFu) << 16);
        a1 += __uint_as_float((unsigned int)u & 0xFFFF0000u);
        a2 += __uint_as_float((unsigned int)((u >> 32) & 0xFFFFu) << 16);
        a3 += __uint_as_float((unsigned int)(u >> 48) << 16);
    }
    if (q < d0 - i) {                     // remainder 0..3 edges, masked by q
        int j = csr[s0 + i + q];
        unsigned long long u = xp8[(long)j * 16 + p];
        a0 += __uint_as_float((unsigned int)(u & 0xFFFFu) << 16);
        a1 += __uint_as_float((unsigned int)u & 0xFFFF0000u);
        a2 += __uint_as_float((unsigned int)((u >> 32) & 0xFFFFu) << 16);
        a3 += __uint_as_float((unsigned int)(u >> 48) << 16);
    }
    a0 += b0; a1 += b1; a2 += b2; a3 += b3;
    a0 += __shfl_xor(a0, 16); a0 += __shfl_xor(a0, 32);
    a1 += __shfl_xor(a1, 16); a1 += __shfl_xor(a1, 32);
    a2 += __shfl_xor(a2, 16); a2 += __shfl_xor(a2, 32);
    a3 += __shfl_xor(a3, 16); a3 += __shfl_xor(a3, 32);
    return (q == 0) ? a0 : (q == 1) ? a1 : (q == 2) ? a2 : a3;
}

// ---- aggregation (layer 1): out[v,:] = relu( dinv[v]*gather + b ), f32 out ----
__global__ void agg_k(const unsigned long long* __restrict__ xp8, const float* __restrict__ dinv,
                      const int* __restrict__ start, const int* __restrict__ csr,
                      const float* __restrict__ bias, float* __restrict__ out, int n) {
    int t = threadIdx.x;
    int lane = t & 63;
    int q = lane >> 4;
    int p = lane & 15;
    int v = blockIdx.x * 4 + (t >> 6);
    if (v >= n) return;
    int s0 = start[v];
    int d0 = start[v + 1] - s0;
    float sum = gather_row(xp8, csr, s0, d0, q, p, v);
    int d = 4 * p + q;
    float val = sum * dinv[v] + bias[d];
    out[(long)v * NDIM + d] = fmaxf(val, 0.f);   // permuted within 256 B row: line-covered
}

// ---- aggpool: chunk=4 nodes/wave, 32x replicated pooled accumulator ----
__global__ void aggpool_k(const unsigned long long* __restrict__ xp8, const float* __restrict__ dinv,
                          const int* __restrict__ start, const int* __restrict__ csr,
                          const float* __restrict__ b2, const int* __restrict__ batch,
                          float* __restrict__ pooledR, int n) {
    int t = threadIdx.x;
    int lane = t & 63;
    int q = lane >> 4, p = lane & 15;
    int wid = blockIdx.x * 4 + (t >> 6);
    int v0 = wid * 4;
    if (v0 >= n) return;
    int v1 = min(v0 + 4, n);
    int d = 4 * p + q;
    float bias = b2[d];
    long rbase = (long)(wid & (NREP - 1)) * (NGRAPH * NDIM);   // replica slice
    int gcur = -1;
    float acc = 0.f;
    for (int v = v0; v < v1; ++v) {                // NOT unrolled: one gather context
        int g = batch[v];                          // wave-uniform broadcast load
        if (g != gcur) {
            if (gcur >= 0) atomicAdd(&pooledR[rbase + gcur * NDIM + d], acc);
            gcur = g;
            acc = 0.f;
        }
        int s0 = start[v];
        int d0 = start[v + 1] - s0;
        float sum = gather_row(xp8, csr, s0, d0, q, p, v);
        acc += fmaxf(sum * dinv[v] + bias, 0.f);
    }
    if (gcur >= 0) atomicAdd(&pooledR[rbase + gcur * NDIM + d], acc);
}

// ---- fold the 32 pooled replicas ----
__global__ void reduce_k(const float* __restrict__ pooledR, float* __restrict__ pooled) {
    int t = blockIdx.x * 256 + threadIdx.x;
    if (t >= NGRAPH * NDIM) return;
    float s = 0.f;
    for (int r = 0; r < NREP; ++r) s += pooledR[(long)r * (NGRAPH * NDIM) + t];
    pooled[t] = s;
}

// ---- head: out[g,c] = (pooled[g,:]/max(cnt,1)) @ Wlin + blin ----
__global__ void final_k(const float* __restrict__ pooled, const int* __restrict__ gstart,
                        const int* __restrict__ gend,
                        const float* __restrict__ Wlin, const float* __restrict__ blin,
                        float* __restrict__ out, int nclass) {
    int t = blockIdx.x * blockDim.x + threadIdx.x;
    if (t >= NGRAPH * nclass) return;
    int g = t / nclass, c = t % nclass;
    float cnt = (float)(gend[g] - gstart[g]);
    float inv = 1.f / fmaxf(cnt, 1.f);
    float acc = 0.f;
    for (int j = 0; j < NDIM; ++j) acc += pooled[g * NDIM + j] * Wlin[j * nclass + c];
    out[t] = acc * inv + blin[c];
}

extern "C" void kernel_launch(void* const* d_in, const int* in_sizes, int n_in,
                              void* d_out, int out_size, void* d_ws, size_t ws_size,
                              hipStream_t stream) {
    const float* x     = (const float*)d_in[0];
    const int*   ei    = (const int*)d_in[1];
    const int*   batch = (const int*)d_in[2];
    const float* W1    = (const float*)d_in[3];
    const float* b1    = (const float*)d_in[4];
    const float* W2    = (const float*)d_in[5];
    const float* b2    = (const float*)d_in[6];
    const float* Wlin  = (const float*)d_in[7];
    const float* blin  = (const float*)d_in[8];
    float* out = (float*)d_out;

    const int N = in_sizes[0] / NDIM;        // 100000
    const int E = in_sizes[1] / 2;           // 1600000
    const int NCLASS = in_sizes[7] / NDIM;   // 10
    const int* src = ei;
    const int* dst = ei + E;
    const int NB   = (N + BNODES - 1) >> BSHIFT;        // 782 buckets (<=1024)
    const int NBLK = (E + ECHUNK - 1) / ECHUNK;         // 196 edge blocks (<=256)

    // ---- workspace carve-out (each 256B-aligned) ----
    size_t o = 0;
    char* wsp = (char*)d_ws;
    auto take = [&](size_t nbytes) -> void* {
        void* p = (void*)(wsp + o);
        o += (nbytes + 255) & ~(size_t)255;
        return p;
    };
    int*   gstart    = (int*)take(NGRAPH * 4);
    int*   gend      = (int*)take(NGRAPH * 4);
    float* pooledR   = (float*)take((size_t)NREP * NGRAPH * NDIM * 4);   // 512 KB
    size_t zero_bytes = o;                    // everything above must start at 0
    float* pooled    = (float*)take(NGRAPH * NDIM * 4);
    int*   cntmat   = (int*)take((size_t)NBLK * NB * 4);
    int*   basemat  = (int*)take((size_t)NBLK * NB * 4);
    int*   bucketTot   = (int*)take((size_t)NB * 4);
    int*   bucketStart = (int*)take((size_t)(NB + 1) * 4);
    float* dinv  = (float*)take((size_t)N * 4);
    int*   start = (int*)take((size_t)(N + 1) * 4);
    int*   csr   = (int*)take((size_t)E * 4);
    unsigned int* ebuf = (unsigned int*)take((size_t)E * 4);
    unsigned int* xws  = (unsigned int*)take((size_t)N * NDIM * 2);   // bf16 pairs
    float* h     = (float*)take((size_t)N * NDIM * 4);
    (void)ws_size;

    hipMemsetAsync(d_ws, 0, zero_bytes, stream);

    int rbl = (N + 3) / 4;                    // 4 nodes per block (agg)
    int gbl = (N + 63) / 64;                  // 64 rows per block (gemm v4)
    int pbl = (N + 15) / 16;                  // aggpool: 4 waves x 4 nodes per block

    // CSR build (deterministic two-pass binning, zero global atomics)
    bincnt_k<<<NBLK, 256, (size_t)NB * 4, stream>>>(dst, cntmat, E, NB);
    colscan_k<<<NB, 256, 0, stream>>>(cntmat, basemat, bucketTot, NBLK, NB);
    bscan_k<<<1, 1024, 0, stream>>>(bucketTot, bucketStart, start, NB, N, E);
    bscatter_k<<<NBLK, 256, (size_t)NB * 4, stream>>>(src, dst, bucketStart, basemat, ebuf, E, NB);
    fill2_k<<<NB, 256, 0, stream>>>(ebuf, bucketStart, batch, dinv, start, csr, gstart, gend, N);

    // layer 1
    gemm_k<<<gbl, 256, 0, stream>>>(x, W1, dinv, (unsigned long long*)xws, N);
    agg_k<<<rbl, 256, 0, stream>>>((const unsigned long long*)xws, dinv, start, csr, b1, h, N);
    // layer 2
    gemm_k<<<gbl, 256, 0, stream>>>(h, W2, dinv, (unsigned long long*)xws, N);
    // fused layer2-agg + replicated register mean-pool
    aggpool_k<<<pbl, 256, 0, stream>>>((const unsigned long long*)xws, dinv, start, csr, b2, batch, pooledR, N);
    reduce_k<<<(NGRAPH * NDIM + 255) / 256, 256, 0, stream>>>(pooledR, pooled);
    // head
    final_k<<<(NGRAPH * NCLASS + 255) / 256, 256, 0, stream>>>(pooled, gstart, gend, Wlin, blin, out, NCLASS);
}